// Round 1
// 424.408 us; speedup vs baseline: 1.0472x; 1.0472x over previous
//
#include <hip/hip_runtime.h>

#define BN 128
#define DTCF 512
#define TT 1024
#define GAF 256
#define DKK 32
#define HID 64
#define NCLS 4
#define LNEPS 1e-5f
#define SCALE 0.17677669529663687f   // 1/sqrt(32)

typedef float f4v __attribute__((ext_vector_type(4)));

// ---------------------------------------------------------------------------
// Kernel 1: fused prep + pass A + softmax. One block per batch (1024 thr,
// thread owns one t, loops all 512 d -> per-t sums complete in-register;
// no partials, softmax done in-block). Blocks [BN, BN+8): W1 transpose.
// Emits u[b,d], muu[b], r[b,t], S2[b], S3[b] for pass B.
// ---------------------------------------------------------------------------
__global__ __launch_bounds__(1024, 4) void k_fusedA(
    const float* __restrict__ tcf, const float* __restrict__ gaf,
    const float* __restrict__ Wq, const float* __restrict__ Wkv,
    const float* __restrict__ Wout, const float* __restrict__ W1,
    float* __restrict__ u, float* __restrict__ muu,
    float* __restrict__ r_o, float* __restrict__ S2, float* __restrict__ S3,
    float* __restrict__ W1t)
{
    int b = blockIdx.x, tid = threadIdx.x;

    if (b >= BN) {                       // W1 transpose: 8 blocks x 4096 elems
        int e0 = (b - BN) * 4096 + tid * 4;
        int j  = e0 >> 9;                // 4 elems stay within one source row
        int dd = e0 & 511;
        #pragma unroll
        for (int i = 0; i < 4; ++i)
            W1t[(dd + i) * HID + j] = W1[j * DTCF + dd + i];
        return;
    }

    __shared__ float gaf_s[GAF];
    __shared__ float kvp[DKK][8];
    __shared__ float kv_s[DKK];
    __shared__ float2 uq_s[DTCF];        // .x = u[d], .y = qv[d]
    __shared__ float red[32];
    __shared__ float stats[2];

    int lane = tid & 63, wv = tid >> 6;

    if (tid < GAF) gaf_s[tid] = gaf[b * GAF + tid];
    __syncthreads();

    // KV[k] = sum_g gaf[g]*Wkv[k,g]  (same 8-partial order as before)
    if ((tid & 31) < 8) {
        int k = tid >> 5, p8 = tid & 7;
        float a = 0.f;
        #pragma unroll
        for (int g = p8 * 32; g < p8 * 32 + 32; ++g)
            a += gaf_s[g] * Wkv[k * GAF + g];
        kvp[k][p8] = a;
    }
    __syncthreads();
    if (tid < DKK) {
        float a = 0.f;
        #pragma unroll
        for (int p = 0; p < 8; ++p) a += kvp[tid][p];
        kv_s[tid] = a;
    }
    __syncthreads();

    // u[d] (threads 0..511) and qv[d] (threads 512..1023); muu/varu over d
    if (tid < DTCF) {
        int d = tid;
        float uu = 0.f;
        #pragma unroll
        for (int k = 0; k < DKK; ++k) uu += kv_s[k] * Wout[d * DKK + k];
        uq_s[d].x = uu;
        u[b * DTCF + d] = uu;
        float su = uu, suu = uu * uu;
        #pragma unroll
        for (int off = 32; off > 0; off >>= 1) {
            su  += __shfl_down(su, off);
            suu += __shfl_down(suu, off);
        }
        if (lane == 0) { red[wv] = su; red[16 + wv] = suu; }
    } else {
        int d = tid - DTCF;
        float qq = 0.f;
        #pragma unroll
        for (int k = 0; k < DKK; ++k) qq += kv_s[k] * Wq[k * DTCF + d];
        uq_s[d].y = qq;
    }
    __syncthreads();
    if (tid == 0) {
        float s = 0.f, ss = 0.f;
        #pragma unroll
        for (int i = 0; i < 8; ++i) { s += red[i]; ss += red[16 + i]; }
        float m = s * (1.f / DTCF);
        stats[0] = m;
        stats[1] = ss * (1.f / DTCF) - m * m;
        muu[b] = m;
    }
    __syncthreads();
    float mu_u = stats[0], var_u = stats[1];

    // main stream: thread owns t = tid; d ascending 0..511 (same FP order
    // as the previous passA+soft combine). 256B/instr coalesced; 16-deep MLP.
    const float* col = tcf + (size_t)b * (DTCF * TT) + tid;
    float sx = 0.f, sxx = 0.f, sxu = 0.f, sxq = 0.f;
    #pragma unroll 16
    for (int d = 0; d < DTCF; ++d) {
        float v = col[d << 10];
        float2 uq = uq_s[d];             // ds_read_b64 broadcast
        sx  += v;
        sxx += v * v;
        sxu += v * uq.x;
        sxq += v * uq.y;
    }

    const float inv_d = 1.f / DTCF;
    float mx = sx * inv_d;
    float vx = sxx * inv_d - mx * mx;
    float cv = sxu * inv_d - mx * mu_u;
    float sc = sxq * SCALE;

    // block max over 1024 t
    float m = sc;
    #pragma unroll
    for (int off = 32; off > 0; off >>= 1) m = fmaxf(m, __shfl_xor(m, off));
    if (lane == 0) red[wv] = m;
    __syncthreads();
    m = red[0];
    #pragma unroll
    for (int i = 1; i < 16; ++i) m = fmaxf(m, red[i]);

    // block sum of exp
    float e = __expf(sc - m);
    float s = e;
    #pragma unroll
    for (int off = 32; off > 0; off >>= 1) s += __shfl_xor(s, off);
    if (lane == 0) red[16 + wv] = s;
    __syncthreads();
    s = 0.f;
    #pragma unroll
    for (int i = 0; i < 16; ++i) s += red[16 + i];
    float inv = 1.f / s;

    float w  = e * inv;
    float vr = vx + 2.f * w * cv + w * w * var_u;
    float rr = rsqrtf(vr + LNEPS);
    r_o[b * TT + tid] = rr;

    // S2 = mean_t(rr*w), S3 = mean_t(rr*mx)
    float s2p = rr * w, s3p = rr * mx;
    #pragma unroll
    for (int off = 32; off > 0; off >>= 1) {
        s2p += __shfl_xor(s2p, off);
        s3p += __shfl_xor(s3p, off);
    }
    __syncthreads();                     // guard red reuse
    if (lane == 0) { red[wv] = s2p; red[16 + wv] = s3p; }
    __syncthreads();
    if (tid == 0) {
        float a2 = 0.f, a3 = 0.f;
        #pragma unroll
        for (int i = 0; i < 16; ++i) { a2 += red[i]; a3 += red[16 + i]; }
        S2[b] = a2 * (1.f / TT);
        S3[b] = a3 * (1.f / TT);
    }
}

// ---------------------------------------------------------------------------
// Kernel 2: pass B. One wave per (b,d) row: dot(r[b,:], tcf[b,d,:]).
// d mapped DESCENDING (most-recently-streamed rows of pass A first -> L3
// hits); tcf via nontemporal loads so our misses don't evict wanted lines.
// ---------------------------------------------------------------------------
__global__ __launch_bounds__(256) void k_passB(
    const float* __restrict__ tcf, const float* __restrict__ r,
    const float* __restrict__ u, const float* __restrict__ muu,
    const float* __restrict__ S2, const float* __restrict__ S3,
    const float* __restrict__ g1, const float* __restrict__ be1,
    float* __restrict__ pooled)
{
    int b = blockIdx.x, yb = blockIdx.y;
    int tid = threadIdx.x, wv = tid >> 6, lane = tid & 63;
    int d = (DTCF - 4) - yb * 4 + wv;    // yb=0 -> d=508..511 (freshest in L3)

    const float* row = tcf + ((size_t)b * DTCF + d) * TT;
    const float* rb  = r + (size_t)b * TT;

    float acc = 0.f;
    #pragma unroll
    for (int i = 0; i < 4; ++i) {
        f4v    x  = __builtin_nontemporal_load((const f4v*)(row + i * 256 + lane * 4));
        float4 rv = *(const float4*)(rb + i * 256 + lane * 4);
        acc += rv.x * x.x + rv.y * x.y + rv.z * x.z + rv.w * x.w;
    }
    for (int off = 32; off > 0; off >>= 1) acc += __shfl_down(acc, off);

    if (lane == 0) {
        float pd = acc * (1.f / TT) - S3[b] + (u[b * DTCF + d] - muu[b]) * S2[b];
        pooled[b * DTCF + d] = g1[d] * pd + be1[d];
    }
}

// ---------------------------------------------------------------------------
// Kernel 3: head. Block = 4 waves; wave wv covers dd-chunk of 128, lane j owns
// hidden unit j via coalesced W1t reads. Wave 0 finishes LN2+ELU+classes.
// ---------------------------------------------------------------------------
__global__ __launch_bounds__(256) void k_head(
    const float* __restrict__ pooled, const float* __restrict__ W1t,
    const float* __restrict__ b1, const float* __restrict__ g2,
    const float* __restrict__ be2, const float* __restrict__ W2,
    const float* __restrict__ b2o, float* __restrict__ out)
{
    int b = blockIdx.x, tid = threadIdx.x;
    int j = tid & 63, wv = tid >> 6;
    __shared__ float p_s[DTCF];
    __shared__ float hred[4][HID];
    for (int i = tid; i < DTCF; i += 256) p_s[i] = pooled[b * DTCF + i];
    __syncthreads();

    float hp = 0.f;
    #pragma unroll 8
    for (int i = 0; i < 128; ++i) {
        int dd = wv * 128 + i;
        hp += p_s[dd] * W1t[dd * HID + j];
    }
    hred[wv][j] = hp;
    __syncthreads();

    if (wv == 0) {
        float h = hred[0][j] + hred[1][j] + hred[2][j] + hred[3][j] + b1[j];
        float mu = h;
        for (int off = 32; off > 0; off >>= 1) mu += __shfl_xor(mu, off);
        mu *= (1.f / HID);
        float df = h - mu;
        float vr = df * df;
        for (int off = 32; off > 0; off >>= 1) vr += __shfl_xor(vr, off);
        vr *= (1.f / HID);
        float hn = df * rsqrtf(vr + LNEPS) * g2[j] + be2[j];
        float he = hn > 0.f ? hn : expm1f(hn);

        #pragma unroll
        for (int c = 0; c < NCLS; ++c) {
            float v = he * W2[c * HID + j];
            for (int off = 32; off > 0; off >>= 1) v += __shfl_xor(v, off);
            if (j == 0) out[b * NCLS + c] = v + b2o[c];
        }
    }
}

extern "C" void kernel_launch(void* const* d_in, const int* in_sizes, int n_in,
                              void* d_out, int out_size, void* d_ws, size_t ws_size,
                              hipStream_t stream)
{
    const float* tcf  = (const float*)d_in[0];
    const float* gaf  = (const float*)d_in[1];
    const float* Wq   = (const float*)d_in[2];
    const float* Wkv  = (const float*)d_in[3];
    const float* Wout = (const float*)d_in[4];
    const float* ln1g = (const float*)d_in[5];
    const float* ln1b = (const float*)d_in[6];
    const float* W1   = (const float*)d_in[7];
    const float* b1   = (const float*)d_in[8];
    const float* ln2g = (const float*)d_in[9];
    const float* ln2b = (const float*)d_in[10];
    const float* W2   = (const float*)d_in[11];
    const float* b2   = (const float*)d_in[12];

    float* ws     = (float*)d_ws;
    float* u      = ws;                   // B*DTCF
    float* muu    = u + BN * DTCF;        // B
    float* r      = muu + BN;             // B*T
    float* S2     = r + BN * TT;          // B
    float* S3     = S2 + BN;              // B
    float* pooled = S3 + BN;              // B*DTCF
    float* W1t    = pooled + BN * DTCF;   // 512*64

    k_fusedA<<<BN + 8, 1024, 0, stream>>>(tcf, gaf, Wq, Wkv, Wout, W1,
                                          u, muu, r, S2, S3, W1t);
    k_passB<<<dim3(BN, DTCF / 4), 256, 0, stream>>>(tcf, r, u, muu, S2, S3,
                                                    ln1g, ln1b, pooled);
    k_head<<<BN, 256, 0, stream>>>(pooled, W1t, b1, ln2g, ln2b, W2, b2,
                                   (float*)d_out);
}